// Round 1
// baseline (312.144 us; speedup 1.0000x reference)
//
#include <hip/hip_runtime.h>

#define TT 2048
#define TS 2048
#define NB 2
#define CC 512
#define NH 8
#define HD 64

typedef __attribute__((ext_vector_type(8))) short s8v;
typedef __attribute__((ext_vector_type(8))) __bf16 bf8v;
typedef __attribute__((ext_vector_type(4))) float f4v;
typedef __attribute__((ext_vector_type(4))) unsigned short us4;

static __device__ __forceinline__ unsigned short f2bf(float f) {
  unsigned int u = __builtin_bit_cast(unsigned int, f);
  u += 0x7FFFu + ((u >> 16) & 1u);   // round-to-nearest-even
  return (unsigned short)(u >> 16);
}

static __device__ __forceinline__ bf8v ld_bf8(const unsigned short* p) {
  return __builtin_bit_cast(bf8v, *(const s8v*)p);
}

static __device__ __forceinline__ f4v mfma16(bf8v a, bf8v b, f4v c) {
  return __builtin_amdgcn_mfma_f32_16x16x32_bf16(a, b, c, 0, 0, 0);
}

// ---------------- weight transpose+convert: WT[n][k] = bf16(W[k][n]) ----------------
__global__ __launch_bounds__(256) void wtrans_k(const float* __restrict__ W,
                                                unsigned short* __restrict__ WT) {
  __shared__ float t[64][65];
  int i0 = blockIdx.x * 64, j0 = blockIdx.y * 64;
  int tx = threadIdx.x & 63, ty = threadIdx.x >> 6;
#pragma unroll
  for (int r = 0; r < 16; r++) {
    int li = ty * 16 + r;
    t[li][tx] = W[(size_t)(i0 + li) * CC + j0 + tx];
  }
  __syncthreads();
#pragma unroll
  for (int r = 0; r < 16; r++) {
    int lj = ty * 16 + r;
    WT[(size_t)(j0 + lj) * CC + i0 + tx] = f2bf(t[tx][lj]);
  }
}

// ---------------- GEMM: C[M=4096,N=512] = A[4096,512] @ W + bias ----------------
// W given as WT[n][k] bf16. 64x64 tile per WG, 4 waves x (16 rows x 64 cols).
template<bool A_IS_F32, bool TRANSV, bool F32OUT>
__global__ __launch_bounds__(256) void gemm_k(const void* __restrict__ Av,
    const unsigned short* __restrict__ WT, const float* __restrict__ bias,
    void* __restrict__ Cout, float scale) {
  int lane = threadIdx.x & 63, wave = threadIdx.x >> 6;
  int quad = lane >> 4, l16 = lane & 15;
  int row0 = blockIdx.x * 64 + wave * 16;
  int n0 = blockIdx.y * 64;
  f4v acc[4] = {{0,0,0,0},{0,0,0,0},{0,0,0,0},{0,0,0,0}};
  const float* Af = (const float*)Av;
  const unsigned short* Ab = (const unsigned short*)Av;
  size_t aoff = (size_t)(row0 + l16) * CC + quad * 8;
  const unsigned short* Wb = WT + (size_t)(n0 + l16) * CC + quad * 8;
  for (int k0 = 0; k0 < CC; k0 += 32) {
    bf8v a;
    if (A_IS_F32) {
      f4v f0 = *(const f4v*)(Af + aoff + k0);
      f4v f1 = *(const f4v*)(Af + aoff + k0 + 4);
      s8v t;
#pragma unroll
      for (int i = 0; i < 4; i++) { t[i] = (short)f2bf(f0[i]); t[i + 4] = (short)f2bf(f1[i]); }
      a = __builtin_bit_cast(bf8v, t);
    } else {
      a = ld_bf8(Ab + aoff + k0);
    }
#pragma unroll
    for (int nt = 0; nt < 4; nt++) {
      bf8v b = ld_bf8(Wb + (size_t)nt * 16 * CC + k0);
      acc[nt] = mfma16(a, b, acc[nt]);
    }
  }
  // epilogue: C/D layout row = quad*4+r, col = nt*16+l16
#pragma unroll
  for (int nt = 0; nt < 4; nt++) {
    int col = n0 + nt * 16 + l16;
    float bcol = bias[col];
    if (F32OUT) {
      float* O = (float*)Cout;
#pragma unroll
      for (int r = 0; r < 4; r++)
        O[(size_t)(row0 + quad * 4 + r) * CC + col] = (acc[nt][r] + bcol) * scale;
    } else if (!TRANSV) {
      unsigned short* O = (unsigned short*)Cout;
#pragma unroll
      for (int r = 0; r < 4; r++)
        O[(size_t)(row0 + quad * 4 + r) * CC + col] = f2bf((acc[nt][r] + bcol) * scale);
    } else {
      // transposed store into VT[b][c][t]; 4 consecutive t per lane -> 8B store
      int rb = row0 + quad * 4;
      int bb = rb >> 11, tt = rb & (TT - 1);
      us4 pk;
#pragma unroll
      for (int r = 0; r < 4; r++) pk[r] = f2bf((acc[nt][r] + bcol) * scale);
      *(us4*)((unsigned short*)Cout + ((size_t)bb * CC + col) * TS + tt) = pk;
    }
  }
}

// ---------------- flash attention ----------------
// grid (TT/64, NB*NH), block 256. wave handles 16 q-rows; 64-key tiles.
__global__ __launch_bounds__(256) void attn_k(const unsigned short* __restrict__ Q,
    const unsigned short* __restrict__ K, const unsigned short* __restrict__ VT,
    const int* __restrict__ mask, unsigned short* __restrict__ Ao) {
  __shared__ unsigned short plds[4][16][72];  // per-wave P scratch, +8 pad
  int lane = threadIdx.x & 63, wave = threadIdx.x >> 6;
  int quad = lane >> 4, l16 = lane & 15;
  int bh = blockIdx.y;
  int b = bh >> 3, h = bh & 7;
  int q0 = blockIdx.x * 64 + wave * 16;

  const unsigned short* qp = Q + (size_t)(b * TT + q0 + l16) * CC + h * HD + quad * 8;
  bf8v qa0 = ld_bf8(qp), qa1 = ld_bf8(qp + 32);

  f4v o[4] = {{0,0,0,0},{0,0,0,0},{0,0,0,0},{0,0,0,0}};
  float m_r[4] = {-1e30f, -1e30f, -1e30f, -1e30f};
  float l_r[4] = {0.f, 0.f, 0.f, 0.f};
  const int* mrow = mask + (size_t)b * TS;
  const unsigned short* Kbase = K + (size_t)(b * TS) * CC + h * HD + quad * 8;
  const unsigned short* Vbase = VT + ((size_t)b * CC + h * HD) * TS + quad * 8;

  for (int kt = 0; kt < TS; kt += 64) {
    // S = Q @ K^T  (Q pre-scaled by 1/8)
    f4v s[4];
#pragma unroll
    for (int nt = 0; nt < 4; nt++) {
      const unsigned short* kp = Kbase + (size_t)(kt + nt * 16 + l16) * CC;
      f4v z = {0, 0, 0, 0};
      z = mfma16(qa0, ld_bf8(kp), z);
      z = mfma16(qa1, ld_bf8(kp + 32), z);
      int key = kt + nt * 16 + l16;
      float pen = (mrow[key] != 0) ? 0.0f : -1e30f;
      s[nt] = z + pen;
    }
    // online softmax per row r (row = quad*4+r; 16 lanes of quad share a row)
    float alpha[4];
#pragma unroll
    for (int r = 0; r < 4; r++) {
      float mx = fmaxf(fmaxf(s[0][r], s[1][r]), fmaxf(s[2][r], s[3][r]));
      mx = fmaxf(mx, __shfl_xor(mx, 1, 64));
      mx = fmaxf(mx, __shfl_xor(mx, 2, 64));
      mx = fmaxf(mx, __shfl_xor(mx, 4, 64));
      mx = fmaxf(mx, __shfl_xor(mx, 8, 64));
      float mnew = fmaxf(m_r[r], mx);
      float al = __expf(m_r[r] - mnew);
      float rs = 0.f;
#pragma unroll
      for (int nt = 0; nt < 4; nt++) {
        float p = __expf(s[nt][r] - mnew);
        s[nt][r] = p;
        rs += p;
      }
      rs += __shfl_xor(rs, 1, 64);
      rs += __shfl_xor(rs, 2, 64);
      rs += __shfl_xor(rs, 4, 64);
      rs += __shfl_xor(rs, 8, 64);
      l_r[r] = l_r[r] * al + rs;
      m_r[r] = mnew;
      alpha[r] = al;
    }
#pragma unroll
    for (int dt = 0; dt < 4; dt++)
#pragma unroll
      for (int r = 0; r < 4; r++) o[dt][r] *= alpha[r];
    // P: C-layout -> A-layout via LDS round-trip
#pragma unroll
    for (int nt = 0; nt < 4; nt++)
#pragma unroll
      for (int r = 0; r < 4; r++)
        plds[wave][quad * 4 + r][nt * 16 + l16] = f2bf(s[nt][r]);
    __syncthreads();
    bf8v pa0 = ld_bf8(&plds[wave][l16][quad * 8]);
    bf8v pa1 = ld_bf8(&plds[wave][l16][32 + quad * 8]);
    // O += P @ V   (V^T[d][t] so B-frags are contiguous)
#pragma unroll
    for (int dt = 0; dt < 4; dt++) {
      const unsigned short* vp = Vbase + (size_t)(dt * 16 + l16) * TS + kt;
      o[dt] = mfma16(pa0, ld_bf8(vp), o[dt]);
      o[dt] = mfma16(pa1, ld_bf8(vp + 32), o[dt]);
    }
    __syncthreads();
  }
  float inv[4];
#pragma unroll
  for (int r = 0; r < 4; r++) inv[r] = 1.0f / l_r[r];
  size_t obase = (size_t)(b * TT + q0 + quad * 4) * CC + h * HD + l16;
#pragma unroll
  for (int dt = 0; dt < 4; dt++)
#pragma unroll
    for (int r = 0; r < 4; r++)
      Ao[obase + (size_t)r * CC + dt * 16] = f2bf(o[dt][r] * inv[r]);
}

extern "C" void kernel_launch(void* const* d_in, const int* in_sizes, int n_in,
                              void* d_out, int out_size, void* d_ws, size_t ws_size,
                              hipStream_t stream) {
  const float* x   = (const float*)d_in[0];
  const float* enc = (const float*)d_in[1];
  const int*   msk = (const int*)d_in[2];
  const float* Wq  = (const float*)d_in[3];
  const float* bq  = (const float*)d_in[4];
  const float* Wk  = (const float*)d_in[5];
  const float* bk  = (const float*)d_in[6];
  const float* Wv  = (const float*)d_in[7];
  const float* bv  = (const float*)d_in[8];
  const float* Wo  = (const float*)d_in[9];
  const float* bo  = (const float*)d_in[10];
  float* out = (float*)d_out;

  char* ws = (char*)d_ws;
  const size_t WSZ = (size_t)CC * CC * 2;          // 512 KB per weight
  unsigned short* WqT  = (unsigned short*)(ws);
  unsigned short* WkT  = (unsigned short*)(ws + WSZ);
  unsigned short* WvT  = (unsigned short*)(ws + 2 * WSZ);
  unsigned short* WoT  = (unsigned short*)(ws + 3 * WSZ);
  unsigned short* Qb   = (unsigned short*)(ws + 4 * WSZ);                    // 4 MB
  unsigned short* Kb   = (unsigned short*)(ws + 4 * WSZ + 4194304);          // 4 MB
  unsigned short* VTb  = (unsigned short*)(ws + 4 * WSZ + 2 * 4194304);      // 4 MB
  unsigned short* Attb = (unsigned short*)(ws + 4 * WSZ + 3 * 4194304);      // 4 MB

  dim3 blk(256);
  wtrans_k<<<dim3(8, 8), blk, 0, stream>>>(Wq, WqT);
  wtrans_k<<<dim3(8, 8), blk, 0, stream>>>(Wk, WkT);
  wtrans_k<<<dim3(8, 8), blk, 0, stream>>>(Wv, WvT);
  wtrans_k<<<dim3(8, 8), blk, 0, stream>>>(Wo, WoT);

  dim3 ggrid(64, 8);  // M=4096/64, N=512/64
  gemm_k<true,  false, false><<<ggrid, blk, 0, stream>>>(x,    WqT, bq, Qb,  0.125f);
  gemm_k<true,  false, false><<<ggrid, blk, 0, stream>>>(enc,  WkT, bk, Kb,  1.0f);
  gemm_k<true,  true,  false><<<ggrid, blk, 0, stream>>>(enc,  WvT, bv, VTb, 1.0f);

  attn_k<<<dim3(TT / 64, NB * NH), blk, 0, stream>>>(Qb, Kb, VTb, msk, Attb);

  gemm_k<false, false, true><<<ggrid, blk, 0, stream>>>(Attb, WoT, bo, out, 1.0f);
}

// Round 2
// 292.828 us; speedup vs baseline: 1.0660x; 1.0660x over previous
//
#include <hip/hip_runtime.h>

#define TT 2048
#define TS 2048
#define NB 2
#define CC 512
#define NH 8
#define HD 64
#define NCH 4                 // split-K chunks over keys
#define KCH (TS / NCH)        // 512 keys per chunk
#define NROW (NB * NH * TT)   // 32768 (b,h,q) rows

typedef __attribute__((ext_vector_type(8))) short s8v;
typedef __attribute__((ext_vector_type(8))) __bf16 bf8v;
typedef __attribute__((ext_vector_type(4))) float f4v;
typedef __attribute__((ext_vector_type(4))) unsigned short us4;

static __device__ __forceinline__ unsigned short f2bf(float f) {
  unsigned int u = __builtin_bit_cast(unsigned int, f);
  u += 0x7FFFu + ((u >> 16) & 1u);   // round-to-nearest-even
  return (unsigned short)(u >> 16);
}
static __device__ __forceinline__ float bf2f(unsigned short u) {
  return __builtin_bit_cast(float, (unsigned int)u << 16);
}
static __device__ __forceinline__ bf8v ld_bf8(const unsigned short* p) {
  return __builtin_bit_cast(bf8v, *(const s8v*)p);
}
static __device__ __forceinline__ f4v mfma16(bf8v a, bf8v b, f4v c) {
  return __builtin_amdgcn_mfma_f32_16x16x32_bf16(a, b, c, 0, 0, 0);
}

// ---------------- all-4 weight transpose+convert: WT[n][k] = bf16(W[k][n]) ----------------
__global__ __launch_bounds__(256) void wtrans_k(const float* __restrict__ W0,
    const float* __restrict__ W1, const float* __restrict__ W2, const float* __restrict__ W3,
    unsigned short* __restrict__ T0, unsigned short* __restrict__ T1,
    unsigned short* __restrict__ T2, unsigned short* __restrict__ T3) {
  const float* Ws[4] = {W0, W1, W2, W3};
  unsigned short* Ts[4] = {T0, T1, T2, T3};
  const float* W = Ws[blockIdx.z];
  unsigned short* WT = Ts[blockIdx.z];
  __shared__ float t[64][65];
  int i0 = blockIdx.x * 64, j0 = blockIdx.y * 64;
  int tx = threadIdx.x & 63, ty = threadIdx.x >> 6;
#pragma unroll
  for (int r = 0; r < 16; r++) {
    int li = ty * 16 + r;
    t[li][tx] = W[(size_t)(i0 + li) * CC + j0 + tx];
  }
  __syncthreads();
#pragma unroll
  for (int r = 0; r < 16; r++) {
    int lj = ty * 16 + r;
    WT[(size_t)(j0 + lj) * CC + i0 + tx] = f2bf(t[tx][lj]);
  }
}

// ---------------- f32 -> bf16 activation convert (x and enc in one launch) ----------------
__global__ __launch_bounds__(256) void cvt_k(const float* __restrict__ x,
    const float* __restrict__ enc, unsigned short* __restrict__ xb,
    unsigned short* __restrict__ eb) {
  size_t i = ((size_t)blockIdx.x * 256 + threadIdx.x) * 4;
  f4v a = *(const f4v*)(x + i);
  f4v b = *(const f4v*)(enc + i);
  us4 pa, pb;
#pragma unroll
  for (int j = 0; j < 4; j++) { pa[j] = f2bf(a[j]); pb[j] = f2bf(b[j]); }
  *(us4*)(xb + i) = pa;
  *(us4*)(eb + i) = pb;
}

// ---------------- GEMM: C[4096,512] = A_bf16[4096,512] @ W + bias ----------------
// WT[n][k] bf16. 64x64 tile/WG, 4 waves x (16 rows x 64 cols).
template<bool F32OUT>
__global__ __launch_bounds__(256) void gemm_k(const unsigned short* __restrict__ A,
    const unsigned short* __restrict__ WT, const float* __restrict__ bias,
    void* __restrict__ Cout, float scale) {
  int lane = threadIdx.x & 63, wave = threadIdx.x >> 6;
  int quad = lane >> 4, l16 = lane & 15;
  int row0 = blockIdx.x * 64 + wave * 16;
  int n0 = blockIdx.y * 64;
  f4v acc[4] = {{0,0,0,0},{0,0,0,0},{0,0,0,0},{0,0,0,0}};
  const unsigned short* Ap = A + (size_t)(row0 + l16) * CC + quad * 8;
  const unsigned short* Wb = WT + (size_t)(n0 + l16) * CC + quad * 8;
#pragma unroll 4
  for (int k0 = 0; k0 < CC; k0 += 32) {
    bf8v a = ld_bf8(Ap + k0);
#pragma unroll
    for (int nt = 0; nt < 4; nt++) {
      bf8v b = ld_bf8(Wb + (size_t)nt * 16 * CC + k0);
      acc[nt] = mfma16(a, b, acc[nt]);
    }
  }
#pragma unroll
  for (int nt = 0; nt < 4; nt++) {
    int col = n0 + nt * 16 + l16;
    float bcol = bias[col];
    if (F32OUT) {
      float* O = (float*)Cout;
#pragma unroll
      for (int r = 0; r < 4; r++)
        O[(size_t)(row0 + quad * 4 + r) * CC + col] = (acc[nt][r] + bcol) * scale;
    } else {
      unsigned short* O = (unsigned short*)Cout;
#pragma unroll
      for (int r = 0; r < 4; r++)
        O[(size_t)(row0 + quad * 4 + r) * CC + col] = f2bf((acc[nt][r] + bcol) * scale);
    }
  }
}

// ---------------- fused K+V GEMM: one A-frag feeds 8 MFMAs; V stored transposed ----------------
__global__ __launch_bounds__(256) void gemmkv_k(const unsigned short* __restrict__ A,
    const unsigned short* __restrict__ WkT, const float* __restrict__ bk,
    const unsigned short* __restrict__ WvT, const float* __restrict__ bv,
    unsigned short* __restrict__ Kout, unsigned short* __restrict__ VTout) {
  int lane = threadIdx.x & 63, wave = threadIdx.x >> 6;
  int quad = lane >> 4, l16 = lane & 15;
  int row0 = blockIdx.x * 64 + wave * 16;
  int n0 = blockIdx.y * 64;
  f4v ak[4] = {{0,0,0,0},{0,0,0,0},{0,0,0,0},{0,0,0,0}};
  f4v av[4] = {{0,0,0,0},{0,0,0,0},{0,0,0,0},{0,0,0,0}};
  const unsigned short* Ap = A + (size_t)(row0 + l16) * CC + quad * 8;
  const unsigned short* Wkb = WkT + (size_t)(n0 + l16) * CC + quad * 8;
  const unsigned short* Wvb = WvT + (size_t)(n0 + l16) * CC + quad * 8;
#pragma unroll 2
  for (int k0 = 0; k0 < CC; k0 += 32) {
    bf8v a = ld_bf8(Ap + k0);
#pragma unroll
    for (int nt = 0; nt < 4; nt++) {
      ak[nt] = mfma16(a, ld_bf8(Wkb + (size_t)nt * 16 * CC + k0), ak[nt]);
      av[nt] = mfma16(a, ld_bf8(Wvb + (size_t)nt * 16 * CC + k0), av[nt]);
    }
  }
#pragma unroll
  for (int nt = 0; nt < 4; nt++) {
    int col = n0 + nt * 16 + l16;
    float bkc = bk[col], bvc = bv[col];
#pragma unroll
    for (int r = 0; r < 4; r++)
      Kout[(size_t)(row0 + quad * 4 + r) * CC + col] = f2bf(ak[nt][r] + bkc);
    // V transposed: VT[b][c][t], 4 consecutive t per lane -> 8B store
    int rb = row0 + quad * 4;
    int bb = rb >> 11, tt = rb & (TT - 1);
    us4 pk;
#pragma unroll
    for (int r = 0; r < 4; r++) pk[r] = f2bf(av[nt][r] + bvc);
    *(us4*)(VTout + ((size_t)bb * CC + col) * TS + tt) = pk;
  }
}

// ---------------- split-K flash attention ----------------
// grid (TT/64, NB*NH, NCH), block 256. wave = 16 q-rows vs KCH keys.
__global__ __launch_bounds__(256) void attn_k(const unsigned short* __restrict__ Q,
    const unsigned short* __restrict__ K, const unsigned short* __restrict__ VT,
    const int* __restrict__ mask, unsigned short* __restrict__ Op,
    float* __restrict__ Mp, float* __restrict__ Lp) {
  __shared__ unsigned short plds[4][16][72];  // wave-private P scratch, +8 pad
  int lane = threadIdx.x & 63, wave = threadIdx.x >> 6;
  int quad = lane >> 4, l16 = lane & 15;
  int bh = blockIdx.y;
  int b = bh >> 3, h = bh & 7;
  int chunk = blockIdx.z;
  int q0 = blockIdx.x * 64 + wave * 16;

  const unsigned short* qp = Q + (size_t)(b * TT + q0 + l16) * CC + h * HD + quad * 8;
  bf8v qa0 = ld_bf8(qp), qa1 = ld_bf8(qp + 32);

  f4v o[4] = {{0,0,0,0},{0,0,0,0},{0,0,0,0},{0,0,0,0}};
  float m_r[4] = {-1e30f, -1e30f, -1e30f, -1e30f};
  float l_r[4] = {0.f, 0.f, 0.f, 0.f};
  const int* mrow = mask + (size_t)b * TS + chunk * KCH;
  const unsigned short* Kbase =
      K + (size_t)(b * TS + chunk * KCH) * CC + h * HD + quad * 8;
  const unsigned short* Vbase =
      VT + ((size_t)b * CC + h * HD) * TS + chunk * KCH + quad * 8;

  for (int kt = 0; kt < KCH; kt += 64) {
    f4v s[4];
#pragma unroll
    for (int nt = 0; nt < 4; nt++) {
      const unsigned short* kp = Kbase + (size_t)(kt + nt * 16 + l16) * CC;
      f4v z = {0, 0, 0, 0};
      z = mfma16(qa0, ld_bf8(kp), z);
      z = mfma16(qa1, ld_bf8(kp + 32), z);
      float pen = (mrow[kt + nt * 16 + l16] != 0) ? 0.0f : -1e30f;
      s[nt] = z + pen;
    }
    float alpha[4];
#pragma unroll
    for (int r = 0; r < 4; r++) {
      float mx = fmaxf(fmaxf(s[0][r], s[1][r]), fmaxf(s[2][r], s[3][r]));
      mx = fmaxf(mx, __shfl_xor(mx, 1, 64));
      mx = fmaxf(mx, __shfl_xor(mx, 2, 64));
      mx = fmaxf(mx, __shfl_xor(mx, 4, 64));
      mx = fmaxf(mx, __shfl_xor(mx, 8, 64));
      float mnew = fmaxf(m_r[r], mx);
      float al = __expf(m_r[r] - mnew);
      float rs = 0.f;
#pragma unroll
      for (int nt = 0; nt < 4; nt++) {
        float p = __expf(s[nt][r] - mnew);
        s[nt][r] = p;
        rs += p;
      }
      rs += __shfl_xor(rs, 1, 64);
      rs += __shfl_xor(rs, 2, 64);
      rs += __shfl_xor(rs, 4, 64);
      rs += __shfl_xor(rs, 8, 64);
      l_r[r] = l_r[r] * al + rs;
      m_r[r] = mnew;
      alpha[r] = al;
    }
#pragma unroll
    for (int dt = 0; dt < 4; dt++)
#pragma unroll
      for (int r = 0; r < 4; r++) o[dt][r] *= alpha[r];
    // P: C-layout -> A-layout via wave-private LDS (no barrier needed)
#pragma unroll
    for (int nt = 0; nt < 4; nt++)
#pragma unroll
      for (int r = 0; r < 4; r++)
        plds[wave][quad * 4 + r][nt * 16 + l16] = f2bf(s[nt][r]);
    bf8v pa0 = ld_bf8(&plds[wave][l16][quad * 8]);
    bf8v pa1 = ld_bf8(&plds[wave][l16][32 + quad * 8]);
#pragma unroll
    for (int dt = 0; dt < 4; dt++) {
      const unsigned short* vp = Vbase + (size_t)(dt * 16 + l16) * TS + kt;
      o[dt] = mfma16(pa0, ld_bf8(vp), o[dt]);
      o[dt] = mfma16(pa1, ld_bf8(vp + 32), o[dt]);
    }
  }
  // store unnormalized partials
  int rowbase = (b * NH + h) * TT + q0 + quad * 4;
  size_t obase = (size_t)chunk * NROW * HD + (size_t)rowbase * HD;
#pragma unroll
  for (int dt = 0; dt < 4; dt++)
#pragma unroll
    for (int r = 0; r < 4; r++)
      Op[obase + (size_t)r * HD + dt * 16 + l16] = f2bf(o[dt][r]);
  if (l16 == 0) {
#pragma unroll
    for (int r = 0; r < 4; r++) {
      Mp[(size_t)chunk * NROW + rowbase + r] = m_r[r];
      Lp[(size_t)chunk * NROW + rowbase + r] = l_r[r];
    }
  }
}

// ---------------- split-K combine: Attb[b][q][h*64+d] ----------------
__global__ __launch_bounds__(256) void combine_k(const unsigned short* __restrict__ Op,
    const float* __restrict__ Mp, const float* __restrict__ Lp,
    unsigned short* __restrict__ Attb) {
  int row = blockIdx.x * 4 + (threadIdx.x >> 6);
  int d = threadIdx.x & 63;
  float m[NCH], l[NCH];
#pragma unroll
  for (int c = 0; c < NCH; c++) {
    m[c] = Mp[(size_t)c * NROW + row];
    l[c] = Lp[(size_t)c * NROW + row];
  }
  float M = fmaxf(fmaxf(m[0], m[1]), fmaxf(m[2], m[3]));
  float L = 0.f, o = 0.f;
#pragma unroll
  for (int c = 0; c < NCH; c++) {
    float w = __expf(m[c] - M);
    L += w * l[c];
    o += w * bf2f(Op[(size_t)c * NROW * HD + (size_t)row * HD + d]);
  }
  int b = row >> 14, h = (row >> 11) & 7, q = row & (TT - 1);
  Attb[((size_t)(b * TT + q)) * CC + h * HD + d] = f2bf(o / L);
}

extern "C" void kernel_launch(void* const* d_in, const int* in_sizes, int n_in,
                              void* d_out, int out_size, void* d_ws, size_t ws_size,
                              hipStream_t stream) {
  const float* x   = (const float*)d_in[0];
  const float* enc = (const float*)d_in[1];
  const int*   msk = (const int*)d_in[2];
  const float* Wq  = (const float*)d_in[3];
  const float* bq  = (const float*)d_in[4];
  const float* Wk  = (const float*)d_in[5];
  const float* bk  = (const float*)d_in[6];
  const float* Wv  = (const float*)d_in[7];
  const float* bv  = (const float*)d_in[8];
  const float* Wo  = (const float*)d_in[9];
  const float* bo  = (const float*)d_in[10];
  float* out = (float*)d_out;

  char* ws = (char*)d_ws;
  const size_t MB = 1024 * 1024;
  unsigned short* WqT  = (unsigned short*)(ws);                 // 512 KB
  unsigned short* WkT  = (unsigned short*)(ws + 512 * 1024);
  unsigned short* WvT  = (unsigned short*)(ws + 1024 * 1024);
  unsigned short* WoT  = (unsigned short*)(ws + 1536 * 1024);
  unsigned short* Qb   = (unsigned short*)(ws + 2 * MB);        // 4 MB
  unsigned short* Kb   = (unsigned short*)(ws + 6 * MB);        // 4 MB
  unsigned short* VTb  = (unsigned short*)(ws + 10 * MB);       // 4 MB
  unsigned short* Attb = (unsigned short*)(ws + 14 * MB);       // 4 MB
  // region R: xb/eb live only until the KV GEMM; Opart overlays them afterwards
  unsigned short* xb   = (unsigned short*)(ws + 18 * MB);       // 4 MB
  unsigned short* eb   = (unsigned short*)(ws + 22 * MB);       // 4 MB
  unsigned short* Opart = (unsigned short*)(ws + 18 * MB);      // 16 MB (overlay)
  float* Mp = (float*)(ws + 34 * MB);                           // 512 KB
  float* Lp = (float*)(ws + 34 * MB + 512 * 1024);              // 512 KB

  dim3 blk(256);
  wtrans_k<<<dim3(8, 8, 4), blk, 0, stream>>>(Wq, Wk, Wv, Wo, WqT, WkT, WvT, WoT);
  cvt_k<<<dim3(2048), blk, 0, stream>>>(x, enc, xb, eb);

  dim3 ggrid(64, 8);  // M=4096/64, N=512/64
  gemm_k<false><<<ggrid, blk, 0, stream>>>(xb, WqT, bq, Qb, 0.125f);
  gemmkv_k<<<ggrid, blk, 0, stream>>>(eb, WkT, bk, WvT, bv, Kb, VTb);

  attn_k<<<dim3(TT / 64, NB * NH, NCH), blk, 0, stream>>>(Qb, Kb, VTb, msk, Opart, Mp, Lp);
  combine_k<<<dim3(NROW / 4), blk, 0, stream>>>(Opart, Mp, Lp, Attb);

  gemm_k<true><<<ggrid, blk, 0, stream>>>(Attb, WoT, bo, out, 1.0f);
}